// Round 6
// baseline (591.869 us; speedup 1.0000x reference)
//
#include <hip/hip_runtime.h>
#include <hip/hip_bf16.h>

typedef __attribute__((ext_vector_type(8))) short bf16x8;
typedef __attribute__((ext_vector_type(4))) float f32x4;
typedef __attribute__((ext_vector_type(8))) unsigned short u16x8;

__device__ __forceinline__ unsigned short bf16_rne(float f) {
  union { float f; unsigned u; } c; c.f = f;
  unsigned u = c.u;
  return (unsigned short)((u + 0x7FFFu + ((u >> 16) & 1u)) >> 16);
}

// one v_cvt_pk_bf16_f32: low16 = bf16(lo), high16 = bf16(hi), RNE
__device__ __forceinline__ unsigned cvt_pk_bf16(float lo, float hi) {
  unsigned r;
  asm("v_cvt_pk_bf16_f32 %0, %1, %2" : "=v"(r) : "v"(lo), "v"(hi));
  return r;
}

// B-fragment load: base is (pack + lane*8); fragment f at byte offset f*1024
#define BFRAG(base, f) (*(const bf16x8*)((base) + (size_t)(f) * 512))

// ---------------- prep: pack D (on-the-fly DCT-II basis), w1^T, w2^T into
// MFMA fragment-linear bf16 layout: [kstep][nfrag][lane][j], element =
// Beff[kstep*32 + (lane>>4)*8 + j][nfrag*16 + (lane&15)] ----------------
__global__ void fecam_prep(const float* __restrict__ w1, const float* __restrict__ w2,
                           unsigned short* __restrict__ Dp, unsigned short* __restrict__ w1p,
                           unsigned short* __restrict__ w2p) {
  int t = blockIdx.x * 256 + threadIdx.x;
  int lane = t & 63;
  int fr = t >> 6;
  int l16 = lane & 15, lh = lane >> 4;
  unsigned short o[8];
  if (fr < 512) {                            // D: K=512 (16 ksteps), N=512 (NF=32)
    int kstep = fr >> 5, nf = fr & 31;
    int n = nf * 16 + l16;
#pragma unroll
    for (int j = 0; j < 8; ++j) {
      int k = kstep * 32 + lh * 8 + j;
      int tt = (n * (2 * k + 1)) & 2047;     // exact angle reduction mod 2*pi
      float v = 2.0f * cosf((float)tt * 3.0679615757712823e-3f); // pi/1024
      o[j] = bf16_rne(v);
    }
    *(u16x8*)(Dp + (size_t)t * 8) = *(u16x8*)o;
  } else if (fr < 1536) {                    // w1^T: K=512 (16 ksteps), N=1024 (NF=64)
    int fr2 = fr - 512;
    int nf = fr2 & 63;
    int kstep = fr2 >> 6;
    int n = nf * 16 + l16;
#pragma unroll
    for (int j = 0; j < 8; ++j) {
      int k = kstep * 32 + lh * 8 + j;
      o[j] = bf16_rne(w1[(size_t)n * 512 + k]);
    }
    *(u16x8*)(w1p + ((size_t)fr2 * 64 + lane) * 8) = *(u16x8*)o;
  } else {                                   // w2^T: K=1024 (32 ksteps), N=512 (NF=32)
    int fr3 = fr - 1536;
    int nf = fr3 & 31;
    int kstep = fr3 >> 5;
    int n = nf * 16 + l16;
#pragma unroll
    for (int j = 0; j < 8; ++j) {
      int k = kstep * 32 + lh * 8 + j;
      o[j] = bf16_rne(w2[(size_t)n * 1024 + k]);
    }
    *(u16x8*)(w2p + ((size_t)fr3 * 64 + lane) * 8) = *(u16x8*)o;
  }
}

// ---------------- fused main: BM=64 rows, 1024 thr = 16 waves.
// GEMM1: wave=64x32. GEMM2: two 512-col halves, wave=64x32 (acc2[4][2], no
// spill). h0 -> bufH, h1 overwrites dead sd. GEMM3: per-half K=512, wave=64x32.
// Depth-2 B-fragment software pipeline in all GEMM loops. LDS 129KB. ----------------
__global__ __launch_bounds__(1024, 4) void fecam_main(
    const float* __restrict__ x, const float* __restrict__ gamma, const float* __restrict__ beta,
    const unsigned short* __restrict__ Dp, const unsigned short* __restrict__ w1p,
    const unsigned short* __restrict__ w2p, float* __restrict__ out) {
  extern __shared__ char smem[];
  // [0, 64K):   bufS: x bf16 [64][512] swz -> sd in place -> h half1
  // [64K,128K): bufH: h half0 [64][512] swz
  char* bufH = smem + 65536;
  float* rs1 = (float*)(smem + 131072);   // [64] LN1 sums
  float* rq1 = rs1 + 64;
  float* rs2 = rq1 + 64;
  float* rq2 = rs2 + 64;

  const int tid = threadIdx.x;
  const int lane = tid & 63;
  const int w = tid >> 6;            // wave 0..15
  const int l16 = lane & 15, lh = lane >> 4;
  const int b = blockIdx.x >> 3;
  const int c0 = (blockIdx.x & 7) * 64;

  if (tid < 256) rs1[tid] = 0.0f;    // zero all 4 stat arrays

  // per-lane weight base pointers (uniform strides -> saddr-friendly)
  const unsigned short* Db = Dp + lane * 8;
  const unsigned short* W1b = w1p + lane * 8;
  const unsigned short* W2b = w2p + lane * 8;

  // ---- phase 0: stage x rows -> bufS bf16 [64][512] swz ----
  {
    const int cc = lane;             // row (c offset)
    const int kg = w;                // k-pair group 0..15
    const float* xb = x + ((size_t)b * 512) * 512 + c0 + cc;
#pragma unroll
    for (int kb = 0; kb < 16; ++kb) {
      int k = kb * 32 + kg * 2;
      unsigned pk = cvt_pk_bf16(xb[(size_t)k * 512], xb[(size_t)(k + 1) * 512]);
      int byte = (cc * 1024 + k * 2) ^ ((cc & 7) << 4);
      *(unsigned*)(smem + byte) = pk;
    }
  }

  float g_[2], b_[2];
#pragma unroll
  for (int jj = 0; jj < 2; ++jj) {
    g_[jj] = gamma[w * 32 + jj * 16 + l16];
    b_[jj] = beta[w * 32 + jj * 16 + l16];
  }

  // ======== GEMM1 + LN1 + sd ========
  {
    f32x4 acc1[4][2];
#pragma unroll
    for (int i = 0; i < 4; ++i)
#pragma unroll
      for (int jj = 0; jj < 2; ++jj) acc1[i][jj] = (f32x4){0.f, 0.f, 0.f, 0.f};

    // B prologue (independent of LDS; overlaps staging drain)
    bf16x8 p0[2], p1[2];
#pragma unroll
    for (int jj = 0; jj < 2; ++jj) {
      p0[jj] = BFRAG(Db, w * 2 + jj);
      p1[jj] = BFRAG(Db, 32 + w * 2 + jj);
    }
    __syncthreads();   // staging visible

    __builtin_amdgcn_s_setprio(1);
#pragma unroll
    for (int k = 0; k < 16; ++k) {
      bf16x8 bc[2] = {p0[0], p0[1]};
      p0[0] = p1[0]; p0[1] = p1[1];
      if (k < 14) {
        p1[0] = BFRAG(Db, (k + 2) * 32 + w * 2);
        p1[1] = BFRAG(Db, (k + 2) * 32 + w * 2 + 1);
      }
      bf16x8 af[4];
#pragma unroll
      for (int i = 0; i < 4; ++i) {
        int r = i * 16 + l16;
        int byte = (r * 1024 + k * 64 + lh * 16) ^ ((r & 7) << 4);
        af[i] = *(const bf16x8*)(smem + byte);
      }
#pragma unroll
      for (int jj = 0; jj < 2; ++jj)
#pragma unroll
        for (int i = 0; i < 4; ++i)
          acc1[i][jj] = __builtin_amdgcn_mfma_f32_16x16x32_bf16(af[i], bc[jj], acc1[i][jj], 0, 0, 0);
    }
    __builtin_amdgcn_s_setprio(0);

    // LN1 stats over this wave's 32 cols -> LDS atomics
#pragma unroll
    for (int i = 0; i < 4; ++i) {
#pragma unroll
      for (int q = 0; q < 4; ++q) {
        float s = acc1[i][0][q] + acc1[i][1][q];
        float ss = acc1[i][0][q] * acc1[i][0][q] + acc1[i][1][q] * acc1[i][1][q];
#pragma unroll
        for (int m = 1; m <= 8; m <<= 1) {
          s += __shfl_xor(s, m);
          ss += __shfl_xor(ss, m);
        }
        if (l16 == 0) {
          atomicAdd(&rs1[i * 16 + lh * 4 + q], s);
          atomicAdd(&rq1[i * 16 + lh * 4 + q], ss);
        }
      }
    }
    __syncthreads();   // all GEMM1 x-reads done; stats complete

    // normalize -> sd bf16 into bufS (overwrites x), paired rows q/q+1
#pragma unroll
    for (int i = 0; i < 4; ++i) {
      float mu_[4], rstd_[4];
#pragma unroll
      for (int q = 0; q < 4; ++q) {
        int r = i * 16 + lh * 4 + q;
        float mu = rs1[r] * (1.0f / 512.0f);
        float var = rq1[r] * (1.0f / 512.0f) - mu * mu;
        mu_[q] = mu;
        rstd_[q] = rsqrtf(var + 1e-6f);
      }
#pragma unroll
      for (int jj = 0; jj < 2; ++jj) {
        int col = w * 32 + jj * 16 + l16;
#pragma unroll
        for (int q = 0; q < 4; q += 2) {
          int r0 = i * 16 + lh * 4 + q;
          float v0 = (acc1[i][jj][q] - mu_[q]) * rstd_[q] * g_[jj] + b_[jj];
          float v1 = (acc1[i][jj][q + 1] - mu_[q + 1]) * rstd_[q + 1] * g_[jj] + b_[jj];
          unsigned pk = cvt_pk_bf16(v0, v1);
          int byte0 = (r0 * 1024 + col * 2) ^ ((r0 & 7) << 4);
          int byte1 = ((r0 + 1) * 1024 + col * 2) ^ (((r0 + 1) & 7) << 4);
          *(unsigned short*)(smem + byte0) = (unsigned short)pk;
          *(unsigned short*)(smem + byte1) = (unsigned short)(pk >> 16);
        }
      }
    }
  }
  __syncthreads();   // sd visible

  // ======== GEMM2/GEMM3 in two 512-col halves of h ========
  f32x4 acc3[4][2];
#pragma unroll
  for (int i = 0; i < 4; ++i)
#pragma unroll
    for (int jj = 0; jj < 2; ++jj) acc3[i][jj] = (f32x4){0.f, 0.f, 0.f, 0.f};

#pragma unroll 1
  for (int half = 0; half < 2; ++half) {
    char* hbuf = (half == 0) ? bufH : smem;   // h1 overwrites dead sd

    // ---- GEMM2 half: wave = 64 rows x 32 cols of this h-half, K=512 (reads sd) ----
    {
      f32x4 acc2[4][2];
#pragma unroll
      for (int i = 0; i < 4; ++i)
#pragma unroll
        for (int jj = 0; jj < 2; ++jj) acc2[i][jj] = (f32x4){0.f, 0.f, 0.f, 0.f};

      bf16x8 p0[2], p1[2];
#pragma unroll
      for (int jj = 0; jj < 2; ++jj) {
        p0[jj] = BFRAG(W1b, half * 32 + w * 2 + jj);
        p1[jj] = BFRAG(W1b, 64 + half * 32 + w * 2 + jj);
      }
      __builtin_amdgcn_s_setprio(1);
#pragma unroll
      for (int k = 0; k < 16; ++k) {
        bf16x8 bc[2] = {p0[0], p0[1]};
        p0[0] = p1[0]; p0[1] = p1[1];
        if (k < 14) {
          p1[0] = BFRAG(W1b, (k + 2) * 64 + half * 32 + w * 2);
          p1[1] = BFRAG(W1b, (k + 2) * 64 + half * 32 + w * 2 + 1);
        }
        bf16x8 af[4];
#pragma unroll
        for (int i = 0; i < 4; ++i) {
          int r = i * 16 + l16;
          int byte = (r * 1024 + k * 64 + lh * 16) ^ ((r & 7) << 4);
          af[i] = *(const bf16x8*)(smem + byte);
        }
#pragma unroll
        for (int jj = 0; jj < 2; ++jj)
#pragma unroll
          for (int i = 0; i < 4; ++i)
            acc2[i][jj] = __builtin_amdgcn_mfma_f32_16x16x32_bf16(af[i], bc[jj], acc2[i][jj], 0, 0, 0);
      }
      __builtin_amdgcn_s_setprio(0);

      if (half == 1) __syncthreads();  // h1 overwrites sd: wait all waves' sd reads

      // relu -> h half bf16 [64][512] swz into hbuf
#pragma unroll
      for (int i = 0; i < 4; ++i) {
#pragma unroll
        for (int jj = 0; jj < 2; ++jj) {
          int lc = w * 32 + jj * 16 + l16;
#pragma unroll
          for (int q = 0; q < 4; q += 2) {
            int r0 = i * 16 + lh * 4 + q;
            float v0 = fmaxf(acc2[i][jj][q], 0.0f);
            float v1 = fmaxf(acc2[i][jj][q + 1], 0.0f);
            unsigned pk = cvt_pk_bf16(v0, v1);
            int byte0 = (r0 * 1024 + lc * 2) ^ ((r0 & 7) << 4);
            int byte1 = ((r0 + 1) * 1024 + lc * 2) ^ (((r0 + 1) & 7) << 4);
            *(unsigned short*)(hbuf + byte0) = (unsigned short)pk;
            *(unsigned short*)(hbuf + byte1) = (unsigned short)(pk >> 16);
          }
        }
      }
    }
    __syncthreads();   // h half visible

    // ---- GEMM3 half: wave = 64 rows x 32 out-cols, K=512 from hbuf ----
    {
      bf16x8 p0[2], p1[2];
#pragma unroll
      for (int jj = 0; jj < 2; ++jj) {
        p0[jj] = BFRAG(W2b, (half * 16) * 32 + w * 2 + jj);
        p1[jj] = BFRAG(W2b, (half * 16 + 1) * 32 + w * 2 + jj);
      }
      __builtin_amdgcn_s_setprio(1);
#pragma unroll
      for (int k = 0; k < 16; ++k) {
        bf16x8 bc[2] = {p0[0], p0[1]};
        p0[0] = p1[0]; p0[1] = p1[1];
        if (k < 14) {
          p1[0] = BFRAG(W2b, (half * 16 + k + 2) * 32 + w * 2);
          p1[1] = BFRAG(W2b, (half * 16 + k + 2) * 32 + w * 2 + 1);
        }
        bf16x8 af[4];
#pragma unroll
        for (int i = 0; i < 4; ++i) {
          int r = i * 16 + l16;
          int byte = (r * 1024 + k * 64 + lh * 16) ^ ((r & 7) << 4);
          af[i] = *(const bf16x8*)(hbuf + byte);
        }
#pragma unroll
        for (int jj = 0; jj < 2; ++jj)
#pragma unroll
          for (int i = 0; i < 4; ++i)
            acc3[i][jj] = __builtin_amdgcn_mfma_f32_16x16x32_bf16(af[i], bc[jj], acc3[i][jj], 0, 0, 0);
      }
      __builtin_amdgcn_s_setprio(0);
    }
  }

  // ---- sigmoid ----
#pragma unroll
  for (int i = 0; i < 4; ++i)
#pragma unroll
    for (int jj = 0; jj < 2; ++jj)
#pragma unroll
      for (int q = 0; q < 4; ++q)
        acc3[i][jj][q] = 1.0f / (1.0f + __expf(-acc3[i][jj][q]));

  // ---- preload x for epilogue (T14: hide HBM latency under LN2 stats) ----
  float4 xv[4][2];
#pragma unroll
  for (int i = 0; i < 4; ++i)
#pragma unroll
    for (int jj = 0; jj < 2; ++jj) {
      int col = w * 32 + jj * 16 + l16;
      size_t base = ((size_t)b * 512 + col) * 512 + c0 + i * 16 + lh * 4;
      xv[i][jj] = *(const float4*)(x + base);
    }

  // ---- LN2 stats ----
#pragma unroll
  for (int i = 0; i < 4; ++i) {
#pragma unroll
    for (int q = 0; q < 4; ++q) {
      float s = acc3[i][0][q] + acc3[i][1][q];
      float ss = acc3[i][0][q] * acc3[i][0][q] + acc3[i][1][q] * acc3[i][1][q];
#pragma unroll
      for (int m = 1; m <= 8; m <<= 1) {
        s += __shfl_xor(s, m);
        ss += __shfl_xor(ss, m);
      }
      if (l16 == 0) {
        atomicAdd(&rs2[i * 16 + lh * 4 + q], s);
        atomicAdd(&rq2[i * 16 + lh * 4 + q], ss);
      }
    }
  }
  __syncthreads();

  // ---- LN2 normalize, multiply by xp, store out[b][col][c0+r] ----
#pragma unroll
  for (int i = 0; i < 4; ++i) {
    float mu_[4], rstd_[4];
#pragma unroll
    for (int q = 0; q < 4; ++q) {
      int r = i * 16 + lh * 4 + q;
      float mu = rs2[r] * (1.0f / 512.0f);
      float var = rq2[r] * (1.0f / 512.0f) - mu * mu;
      mu_[q] = mu;
      rstd_[q] = rsqrtf(var + 1e-6f);
    }
#pragma unroll
    for (int jj = 0; jj < 2; ++jj) {
      int col = w * 32 + jj * 16 + l16;
      size_t base = ((size_t)b * 512 + col) * 512 + c0 + i * 16 + lh * 4;
      float4 ov;
#pragma unroll
      for (int q = 0; q < 4; ++q) {
        float fn = (acc3[i][jj][q] - mu_[q]) * rstd_[q] * g_[jj] + b_[jj];
        (&ov.x)[q] = (&xv[i][jj].x)[q] * fn;
      }
      *(float4*)(out + base) = ov;
    }
  }
}

extern "C" void kernel_launch(void* const* d_in, const int* in_sizes, int n_in,
                              void* d_out, int out_size, void* d_ws, size_t ws_size,
                              hipStream_t stream) {
  const float* x = (const float*)d_in[0];
  const float* gamma = (const float*)d_in[1];
  const float* beta = (const float*)d_in[2];
  const float* w1 = (const float*)d_in[3];
  const float* w2 = (const float*)d_in[4];

  unsigned short* Dp = (unsigned short*)d_ws;        // 16*32*64*8  = 262144 bf16
  unsigned short* w1p = Dp + 262144;                 // 16*64*64*8  = 524288 bf16
  unsigned short* w2p = w1p + 524288;                // 32*32*64*8  = 524288 bf16

  fecam_prep<<<640, 256, 0, stream>>>(w1, w2, Dp, w1p, w2p);
  fecam_main<<<1024, 1024, 132096, stream>>>(x, gamma, beta, Dp, w1p, w2p, (float*)d_out);
}

// Round 7
// 362.061 us; speedup vs baseline: 1.6347x; 1.6347x over previous
//
#include <hip/hip_runtime.h>
#include <hip/hip_bf16.h>

typedef __attribute__((ext_vector_type(8))) short bf16x8;
typedef __attribute__((ext_vector_type(4))) float f32x4;
typedef __attribute__((ext_vector_type(8))) unsigned short u16x8;

__device__ __forceinline__ unsigned short bf16_rne(float f) {
  union { float f; unsigned u; } c; c.f = f;
  unsigned u = c.u;
  return (unsigned short)((u + 0x7FFFu + ((u >> 16) & 1u)) >> 16);
}

// one v_cvt_pk_bf16_f32: low16 = bf16(lo), high16 = bf16(hi), RNE
__device__ __forceinline__ unsigned cvt_pk_bf16(float lo, float hi) {
  unsigned r;
  asm("v_cvt_pk_bf16_f32 %0, %1, %2" : "=v"(r) : "v"(lo), "v"(hi));
  return r;
}

__device__ __forceinline__ bf16x8 pack4(unsigned a, unsigned b, unsigned c, unsigned d) {
  union { unsigned u[4]; bf16x8 v; } t;
  t.u[0] = a; t.u[1] = b; t.u[2] = c; t.u[3] = d;
  return t.v;
}

// ===================== prep0 =====================
// task A (fr<512):    Dbf pack for prep-GEMM B-operand:
//                     Dbf[((ks*32+lf)*64+lane)*8+j] = D[ks*32+lh*8+j][lf*16+l16]
// task B (fr<1536):   w2^T pack (K=1024: 32 ksteps, N=512: 32 nfrags)
// task C (fr<1552):   Gv[n]=sum_k g[k]w1[n][k], Bv[n]=sum_k b[k]w1[n][k]
// task D (fr<1560):   dsum[l] = sum_k D[k][l]
__global__ void fecam_prep0(const float* __restrict__ w1, const float* __restrict__ w2,
                            const float* __restrict__ g, const float* __restrict__ bb,
                            unsigned short* __restrict__ Dbf, unsigned short* __restrict__ w2p,
                            float* __restrict__ Gv, float* __restrict__ Bv,
                            float* __restrict__ dsum) {
  int t = blockIdx.x * 256 + threadIdx.x;
  int lane = t & 63;
  int fr = t >> 6;
  int l16 = lane & 15, lh = lane >> 4;
  if (fr < 512) {            // Dbf: D[k][l], k = ks*32+lh*8+j, l = lf*16+l16
    int ks = fr >> 5, lf = fr & 31;
    int l = lf * 16 + l16;
    unsigned short o[8];
#pragma unroll
    for (int j = 0; j < 8; ++j) {
      int k = ks * 32 + lh * 8 + j;
      int tt = (k * (2 * l + 1)) & 2047;
      o[j] = bf16_rne(2.0f * cosf((float)tt * 3.0679615757712823e-3f));
    }
    *(u16x8*)(Dbf + (size_t)t * 8) = *(u16x8*)o;
  } else if (fr < 1536) {    // w2 pack
    int fr2 = fr - 512;
    int nf = fr2 & 31;
    int ks = fr2 >> 5;
    int n = nf * 16 + l16;
    unsigned short o[8];
#pragma unroll
    for (int j = 0; j < 8; ++j) {
      int k = ks * 32 + lh * 8 + j;
      o[j] = bf16_rne(w2[(size_t)n * 1024 + k]);
    }
    *(u16x8*)(w2p + ((size_t)fr2 * 64 + lane) * 8) = *(u16x8*)o;
  } else if (fr < 1552) {    // Gv, Bv
    int n = (fr - 1536) * 64 + lane;
    float sg = 0.f, sb = 0.f;
    const float* wr = w1 + (size_t)n * 512;
#pragma unroll 4
    for (int k = 0; k < 512; k += 4) {
      float4 wv = *(const float4*)(wr + k);
      float4 gv = *(const float4*)(g + k);
      float4 bv = *(const float4*)(bb + k);
      sg += wv.x * gv.x + wv.y * gv.y + wv.z * gv.z + wv.w * gv.w;
      sb += wv.x * bv.x + wv.y * bv.y + wv.z * bv.z + wv.w * bv.w;
    }
    Gv[n] = sg; Bv[n] = sb;
  } else if (fr < 1560) {    // dsum
    int l = (fr - 1552) * 64 + lane;
    float s = 0.f;
    for (int k = 0; k < 512; ++k) {
      int tt = (k * (2 * l + 1)) & 2047;
      s += 2.0f * cosf((float)tt * 3.0679615757712823e-3f);
    }
    dsum[l] = s;
  }
}

// ===================== prep1: W1D = (w1 . g) @ D, packed =====================
// 256 blocks x 64 thr (1 wave). Block: n0 = (bi>>2)*16 (16 n-rows), l0 = (bi&3)*128.
// Output W1Dp[ks' = l/32][nf' = n/16][lane][8] = W1D[nf*16+l16][ks*32+lh*8+j]
__global__ void fecam_prep1(const float* __restrict__ w1, const float* __restrict__ g,
                            const unsigned short* __restrict__ Dbf,
                            unsigned short* __restrict__ W1Dp) {
  __shared__ float Cl[16][132];
  const int lane = threadIdx.x & 63;
  const int l16 = lane & 15, lh = lane >> 4;
  const int bi = blockIdx.x;
  const int n0 = (bi >> 2) * 16;
  const int l0 = (bi & 3) * 128;

  f32x4 acc[8];
#pragma unroll
  for (int jn = 0; jn < 8; ++jn) acc[jn] = (f32x4){0.f, 0.f, 0.f, 0.f};

  for (int ks = 0; ks < 16; ++ks) {
    int kbase = ks * 32 + lh * 8;
    const float* wr = w1 + (size_t)(n0 + l16) * 512 + kbase;
    float4 wa = *(const float4*)(wr);
    float4 wb = *(const float4*)(wr + 4);
    float4 ga = *(const float4*)(g + kbase);
    float4 gb = *(const float4*)(g + kbase + 4);
    bf16x8 af = pack4(cvt_pk_bf16(wa.x * ga.x, wa.y * ga.y),
                      cvt_pk_bf16(wa.z * ga.z, wa.w * ga.w),
                      cvt_pk_bf16(wb.x * gb.x, wb.y * gb.y),
                      cvt_pk_bf16(wb.z * gb.z, wb.w * gb.w));
#pragma unroll
    for (int jn = 0; jn < 8; ++jn) {
      bf16x8 bf = *(const bf16x8*)(Dbf + (((size_t)ks * 32 + (l0 >> 4) + jn) * 64 + lane) * 8);
      acc[jn] = __builtin_amdgcn_mfma_f32_16x16x32_bf16(af, bf, acc[jn], 0, 0, 0);
    }
  }
  // C[row n-local = lh*4+q][col l-local = jn*16+l16]
#pragma unroll
  for (int jn = 0; jn < 8; ++jn)
#pragma unroll
    for (int q = 0; q < 4; ++q) Cl[lh * 4 + q][jn * 16 + l16] = acc[jn][q];
  __syncthreads();
  // pack: lane emits W1D[n = n0+l16][l = l0 + ks2*32 + lh*8 + j]
#pragma unroll
  for (int ks2 = 0; ks2 < 4; ++ks2) {
    float v[8];
#pragma unroll
    for (int j = 0; j < 8; ++j) v[j] = Cl[l16][ks2 * 32 + lh * 8 + j];
    unsigned short o[8];
#pragma unroll
    for (int j = 0; j < 8; j += 2) {
      unsigned pk = cvt_pk_bf16(v[j], v[j + 1]);
      o[j] = (unsigned short)pk;
      o[j + 1] = (unsigned short)(pk >> 16);
    }
    size_t idx = (((size_t)((l0 >> 5) + ks2) * 64 + (n0 >> 4)) * 64 + lane) * 8;
    *(u16x8*)(W1Dp + idx) = *(u16x8*)o;
  }
}

// ===================== fused main =====================
// BM=64 rows, 1024 thr = 16 waves. Phases:
//  stage x (+row stats s1,s2,x.dsum) -> bufA
//  G2' half0: x @ W1Dp (n 0..511),  h0 = relu(affine) -> bufB
//  G2' half1: (n 512..1023), bar, h1 -> bufA (x dead)
//  G3: h @ w2p (K=1024 over bufB,bufA) -> sigmoid -> LN2 -> * x -> out
// 5 barriers, max live regs ~107 (no spills). LDS 129.25KB -> 1 block/CU.
__global__ __launch_bounds__(1024, 4) void fecam_main(
    const float* __restrict__ x, const float* __restrict__ gamma, const float* __restrict__ beta,
    const unsigned short* __restrict__ W1Dp, const unsigned short* __restrict__ w2p,
    const float* __restrict__ Gv, const float* __restrict__ Bv,
    const float* __restrict__ dsum, float* __restrict__ out) {
  extern __shared__ char smem[];
  char* bufA = smem;                 // x bf16 [64][512] swz -> h half1
  char* bufB = smem + 65536;         // h half0 [64][512] swz
  float* ra = (float*)(smem + 131072);  // [64] sum x
  float* rb = ra + 64;                   // sum x^2
  float* rc = rb + 64;                   // sum x*dsum
  float* rs2 = rc + 64;                  // LN2 sums
  float* rq2 = rs2 + 64;                 // LN2 sumsq

  const int tid = threadIdx.x;
  const int lane = tid & 63;
  const int w = tid >> 6;            // wave 0..15
  const int l16 = lane & 15, lh = lane >> 4;
  const int b = blockIdx.x >> 3;
  const int c0 = (blockIdx.x & 7) * 64;

  if (tid < 320) ra[tid] = 0.0f;     // zero all 5 stat arrays
  __syncthreads();                   // bar0: zeroing visible before atomics

  // ---- stage x -> bufA bf16 [64][512] swz; accumulate row stats ----
  {
    const int cc = lane;             // row (c offset)
    const int kg = w;                // k-pair group 0..15
    const float* xb = x + ((size_t)b * 512) * 512 + c0 + cc;
    float s1 = 0.f, s2 = 0.f, sdp = 0.f;
#pragma unroll
    for (int kb = 0; kb < 16; ++kb) {
      int k = kb * 32 + kg * 2;
      float v0 = xb[(size_t)k * 512];
      float v1 = xb[(size_t)(k + 1) * 512];
      float2 dv = *(const float2*)(dsum + k);
      s1 += v0 + v1;
      s2 += v0 * v0 + v1 * v1;
      sdp += v0 * dv.x + v1 * dv.y;
      unsigned pk = cvt_pk_bf16(v0, v1);
      int byte = (cc * 1024 + k * 2) ^ ((cc & 7) << 4);
      *(unsigned*)(bufA + byte) = pk;
    }
    atomicAdd(&ra[cc], s1);
    atomicAdd(&rb[cc], s2);
    atomicAdd(&rc[cc], sdp);
  }

  // per-wave constants (overlap staging latency)
  float g_[2], b_[2], Gn_[2][2], Bn_[2][2];
#pragma unroll
  for (int jj = 0; jj < 2; ++jj) {
    g_[jj] = gamma[w * 32 + jj * 16 + l16];
    b_[jj] = beta[w * 32 + jj * 16 + l16];
  }
#pragma unroll
  for (int hh = 0; hh < 2; ++hh)
#pragma unroll
    for (int jj = 0; jj < 2; ++jj) {
      int n = hh * 512 + w * 32 + jj * 16 + l16;
      Gn_[hh][jj] = Gv[n];
      Bn_[hh][jj] = Bv[n];
    }

  __syncthreads();                   // bar1: x + stats visible

  f32x4 acc3[4][2];
#pragma unroll
  for (int i = 0; i < 4; ++i)
#pragma unroll
    for (int jj = 0; jj < 2; ++jj) acc3[i][jj] = (f32x4){0.f, 0.f, 0.f, 0.f};

  // ======== G2' two halves (full unroll -> static indices) ========
#pragma unroll
  for (int half = 0; half < 2; ++half) {
    f32x4 acc2[4][2];
#pragma unroll
    for (int i = 0; i < 4; ++i)
#pragma unroll
      for (int jj = 0; jj < 2; ++jj) acc2[i][jj] = (f32x4){0.f, 0.f, 0.f, 0.f};

#pragma unroll 2
    for (int ks = 0; ks < 16; ++ks) {
      bf16x8 af[4];
#pragma unroll
      for (int i = 0; i < 4; ++i) {
        int r = i * 16 + l16;
        int byte = (r * 1024 + ks * 64 + lh * 16) ^ ((r & 7) << 4);
        af[i] = *(const bf16x8*)(bufA + byte);
      }
#pragma unroll
      for (int jj = 0; jj < 2; ++jj) {
        bf16x8 bf = *(const bf16x8*)(
            W1Dp + (((size_t)ks * 64 + half * 32 + w * 2 + jj) * 64 + lane) * 8);
#pragma unroll
        for (int i = 0; i < 4; ++i)
          acc2[i][jj] = __builtin_amdgcn_mfma_f32_16x16x32_bf16(af[i], bf, acc2[i][jj], 0, 0, 0);
      }
    }

    if (half == 1) __syncthreads();  // bar2: all x reads done before overwrite

    char* hbuf = half ? bufA : bufB;
    // h = relu(rstd*acc2 - rstd*mu*Gn + Bn), write bf16 swz
#pragma unroll
    for (int i = 0; i < 4; ++i) {
      float mu_[4], rstd_[4];
#pragma unroll
      for (int q = 0; q < 4; ++q) {
        int r = i * 16 + lh * 4 + q;
        float s1 = ra[r], s2v = rb[r];
        float mu = rc[r] * (1.0f / 512.0f);
        float var = s1 * s1 * (1.0f / 256.0f) + 2.0f * s2v - mu * mu;
        mu_[q] = mu;
        rstd_[q] = rsqrtf(var + 1e-6f);
      }
#pragma unroll
      for (int jj = 0; jj < 2; ++jj) {
        int lc = w * 32 + jj * 16 + l16;
#pragma unroll
        for (int q = 0; q < 4; q += 2) {
          int r0 = i * 16 + lh * 4 + q;
          float c00 = fmaf(-rstd_[q] * mu_[q], Gn_[half][jj], Bn_[half][jj]);
          float c01 = fmaf(-rstd_[q + 1] * mu_[q + 1], Gn_[half][jj], Bn_[half][jj]);
          float v0 = fmaxf(fmaf(acc2[i][jj][q], rstd_[q], c00), 0.0f);
          float v1 = fmaxf(fmaf(acc2[i][jj][q + 1], rstd_[q + 1], c01), 0.0f);
          unsigned pk = cvt_pk_bf16(v0, v1);
          int byte0 = (r0 * 1024 + lc * 2) ^ ((r0 & 7) << 4);
          int byte1 = ((r0 + 1) * 1024 + lc * 2) ^ (((r0 + 1) & 7) << 4);
          *(unsigned short*)(hbuf + byte0) = (unsigned short)pk;
          *(unsigned short*)(hbuf + byte1) = (unsigned short)(pk >> 16);
        }
      }
    }
  }
  __syncthreads();                   // bar3: h complete

  // ======== G3: fw = h @ w2^T, K=1024 (bufB: k 0..511, bufA: k 512..1023) ========
#pragma unroll 2
  for (int ks = 0; ks < 16; ++ks) {
    bf16x8 af[4];
#pragma unroll
    for (int i = 0; i < 4; ++i) {
      int r = i * 16 + l16;
      int byte = (r * 1024 + ks * 64 + lh * 16) ^ ((r & 7) << 4);
      af[i] = *(const bf16x8*)(bufB + byte);
    }
#pragma unroll
    for (int jj = 0; jj < 2; ++jj) {
      bf16x8 bf = *(const bf16x8*)(w2p + (((size_t)ks * 32 + w * 2 + jj) * 64 + lane) * 8);
#pragma unroll
      for (int i = 0; i < 4; ++i)
        acc3[i][jj] = __builtin_amdgcn_mfma_f32_16x16x32_bf16(af[i], bf, acc3[i][jj], 0, 0, 0);
    }
  }
#pragma unroll 2
  for (int ks = 0; ks < 16; ++ks) {
    bf16x8 af[4];
#pragma unroll
    for (int i = 0; i < 4; ++i) {
      int r = i * 16 + l16;
      int byte = (r * 1024 + ks * 64 + lh * 16) ^ ((r & 7) << 4);
      af[i] = *(const bf16x8*)(bufA + byte);
    }
#pragma unroll
    for (int jj = 0; jj < 2; ++jj) {
      bf16x8 bf = *(const bf16x8*)(
          w2p + (((size_t)(16 + ks) * 32 + w * 2 + jj) * 64 + lane) * 8);
#pragma unroll
      for (int i = 0; i < 4; ++i)
        acc3[i][jj] = __builtin_amdgcn_mfma_f32_16x16x32_bf16(af[i], bf, acc3[i][jj], 0, 0, 0);
    }
  }

  // ---- sigmoid ----
#pragma unroll
  for (int i = 0; i < 4; ++i)
#pragma unroll
    for (int jj = 0; jj < 2; ++jj)
#pragma unroll
      for (int q = 0; q < 4; ++q)
        acc3[i][jj][q] = 1.0f / (1.0f + __expf(-acc3[i][jj][q]));

  // ---- LN2 stats ----
#pragma unroll
  for (int i = 0; i < 4; ++i) {
#pragma unroll
    for (int q = 0; q < 4; ++q) {
      float s = acc3[i][0][q] + acc3[i][1][q];
      float ss = acc3[i][0][q] * acc3[i][0][q] + acc3[i][1][q] * acc3[i][1][q];
#pragma unroll
      for (int m = 1; m <= 8; m <<= 1) {
        s += __shfl_xor(s, m);
        ss += __shfl_xor(ss, m);
      }
      if (l16 == 0) {
        atomicAdd(&rs2[i * 16 + lh * 4 + q], s);
        atomicAdd(&rq2[i * 16 + lh * 4 + q], ss);
      }
    }
  }
  __syncthreads();                   // bar4

  // ---- LN2 normalize, multiply by xp, store out[b][col][c0+r] ----
#pragma unroll
  for (int i = 0; i < 4; ++i) {
    float mu_[4], rstd_[4];
#pragma unroll
    for (int q = 0; q < 4; ++q) {
      int r = i * 16 + lh * 4 + q;
      float mu = rs2[r] * (1.0f / 512.0f);
      float var = rq2[r] * (1.0f / 512.0f) - mu * mu;
      mu_[q] = mu;
      rstd_[q] = rsqrtf(var + 1e-6f);
    }
#pragma unroll
    for (int jj = 0; jj < 2; ++jj) {
      int col = w * 32 + jj * 16 + l16;
      size_t base = ((size_t)b * 512 + col) * 512 + c0 + i * 16 + lh * 4;
      float4 xv = *(const float4*)(x + base);
      float4 ov;
#pragma unroll
      for (int q = 0; q < 4; ++q) {
        float fn = (acc3[i][jj][q] - mu_[q]) * rstd_[q] * g_[jj] + b_[jj];
        (&ov.x)[q] = (&xv.x)[q] * fn;
      }
      *(float4*)(out + base) = ov;
    }
  }
}

extern "C" void kernel_launch(void* const* d_in, const int* in_sizes, int n_in,
                              void* d_out, int out_size, void* d_ws, size_t ws_size,
                              hipStream_t stream) {
  const float* x = (const float*)d_in[0];
  const float* gamma = (const float*)d_in[1];
  const float* beta = (const float*)d_in[2];
  const float* w1 = (const float*)d_in[3];
  const float* w2 = (const float*)d_in[4];

  unsigned short* w2p = (unsigned short*)d_ws;       // 524288 bf16
  unsigned short* W1Dp = w2p + 524288;               // 524288 bf16
  unsigned short* Dbf = W1Dp + 524288;               // 262144 bf16
  float* Gv = (float*)(Dbf + 262144);                // 1024 f32
  float* Bv = Gv + 1024;                             // 1024 f32
  float* dsum = Bv + 1024;                           // 512 f32

  fecam_prep0<<<390, 256, 0, stream>>>(w1, w2, gamma, beta, Dbf, w2p, Gv, Bv, dsum);
  fecam_prep1<<<256, 64, 0, stream>>>(w1, gamma, Dbf, W1Dp);
  fecam_main<<<1024, 1024, 132416, stream>>>(x, gamma, beta, W1Dp, w2p, Gv, Bv, dsum,
                                             (float*)d_out);
}